// Round 10
// baseline (55.859 us; speedup 1.0000x reference)
//
#include <hip/hip_runtime.h>

#define DIM   256
#define CLS   512
#define NGF   32640          // packed strict-upper-triangle floats per class
#define NITER 5
#define PSH   72             // part stride in h16 (144 B, 16B-aligned, 36 dw ≡ 4 mod 32)
#define RSH   296            // row stride in h16 (592 B, 16B-aligned, 148 dw ≡ 20 mod 32)

typedef _Float16 h16;
typedef __attribute__((ext_vector_type(2))) _Float16 h16x2;

__device__ __forceinline__ float dot2f(unsigned a, unsigned b, float c) {
    return __builtin_amdgcn_fdot2(__builtin_bit_cast(h16x2, a),
                                  __builtin_bit_cast(h16x2, b), c, false);
}

__device__ __forceinline__ unsigned pkrtz(float lo, float hi) {
    return __builtin_bit_cast(unsigned, __builtin_amdgcn_cvt_pkrtz(lo, hi));
}

// barrier draining LDS only
__device__ __forceinline__ void bar_lds() {
    asm volatile("s_waitcnt lgkmcnt(0)\n\ts_barrier" ::: "memory");
}

__device__ __forceinline__ int cidx(int m) { return (m >> 6) * PSH + (m & 63); }

__global__ void __launch_bounds__(1024)
cayley_kernel(const float* __restrict__ x, const float* __restrict__ W,
              float* __restrict__ out) {
    extern __shared__ char smem[];
    unsigned short* Lh = (unsigned short*)smem;        // expanded f16 S: 256*592 = 151552 B
    h16* sy0 = (h16*)(smem + DIM * RSH * 2);           // 576 B
    h16* sy1 = sy0 + 4 * PSH;                          // 576 B

    const int tid = threadIdx.x;
    const int r   = tid >> 2;        // row 0..255
    const int p   = tid & 3;         // part 0..3 (cols 64p..64p+63)
    const int c   = blockIdx.x;
    const int offr = (r * (511 - r)) / 2 - r - 1;      // off(r) - r - 1

    const float* Wc = W + (size_t)c * NGF;
    const float xr  = x[(size_t)r * CLS + c];

    // zero own diagonal (expansion never touches diagonals)
    if (p == (r >> 6)) Lh[r * RSH + cidx(r)] = 0;

    // ===== expand: thread (r,p) owns upper run (r,g), g in (r,256) ∩ [64p,64p+64) =====
    // reads its contiguous packed slice DIRECTLY from global (L1-friendly: per-lane
    // sequential), writes +0.5w to L[r][g] (adjacent h16) and -0.5w to L[g][r].
    {
        int gbeg = 64 * p;
        if (gbeg <= r) gbeg = r + 1;
        const int gend = 64 * p + 64;
        int g = gbeg;
        if ((g & 1) && g < gend) {                     // peel to even alignment
            float w = Wc[offr + g];
            unsigned hu = pkrtz(0.5f * w, 0.f) & 0xffffu;
            Lh[r * RSH + p * PSH + (g - 64 * p)] = (unsigned short)hu;
            Lh[g * RSH + cidx(r)] = (unsigned short)(hu ^ 0x8000u);
            ++g;
        }
        for (; g < gend; g += 2) {
            float w0 = Wc[offr + g];
            float w1 = Wc[offr + g + 1];
            unsigned pk = pkrtz(0.5f * w0, 0.5f * w1);
            // upper: two adjacent h16 = one aligned b32 write
            *(unsigned*)(Lh + r * RSH + p * PSH + (g - 64 * p)) = pk;
            // lower: negated, rows g and g+1, column r
            Lh[(g)     * RSH + cidx(r)] = (unsigned short)((pk & 0xffffu) ^ 0x8000u);
            Lh[(g + 1) * RSH + cidx(r)] = (unsigned short)((pk >> 16)    ^ 0x8000u);
        }
    }
    if (p == 0) sy0[cidx(r)] = (h16)xr;
    __syncthreads();                                   // expansion complete

    // ===== row slice -> registers: 8 aligned ds_read_b128, no repack needed =====
    unsigned sreg[32];
    {
        const uint4* rowp = (const uint4*)((const char*)smem +
                                           (size_t)r * (RSH * 2) + p * (PSH * 2));
        #pragma unroll
        for (int k = 0; k < 8; ++k) {
            uint4 v = rowp[k];
            sreg[4 * k + 0] = v.x; sreg[4 * k + 1] = v.y;
            sreg[4 * k + 2] = v.z; sreg[4 * k + 3] = v.w;
        }
    }

    // ===== fixed-point iteration y <- x - S y ; out = x - 2 S y =====
    {
        h16* ycur = sy0;
        h16* ynxt = sy1;
        for (int it = 0; it < NITER; ++it) {
            const uint4* yp = (const uint4*)(ycur + p * PSH);
            float a0 = 0.f, a1 = 0.f, a2 = 0.f, a3 = 0.f;
            #pragma unroll
            for (int k = 0; k < 8; ++k) {
                uint4 yv = yp[k];
                a0 = dot2f(sreg[4 * k + 0], yv.x, a0);
                a1 = dot2f(sreg[4 * k + 1], yv.y, a1);
                a2 = dot2f(sreg[4 * k + 2], yv.z, a2);
                a3 = dot2f(sreg[4 * k + 3], yv.w, a3);
            }
            float v = (a0 + a1) + (a2 + a3);           // partial (S y)_r
            v += __shfl_xor(v, 1);
            v += __shfl_xor(v, 2);                     // full (S y)_r on 4 lanes
            if (it < NITER - 1) {
                if (p == 0) ynxt[cidx(r)] = (h16)(xr - v);
                h16* t = ycur; ycur = ynxt; ynxt = t;
                bar_lds();
            } else {
                if (p == 0) out[(size_t)r * CLS + c] = xr - 2.f * v;
            }
        }
    }
}

extern "C" void kernel_launch(void* const* d_in, const int* in_sizes, int n_in,
                              void* d_out, int out_size, void* d_ws, size_t ws_size,
                              hipStream_t stream) {
    const float* x = (const float*)d_in[0];
    const float* W = (const float*)d_in[1];
    float* out = (float*)d_out;

    const size_t smem = (size_t)DIM * RSH * 2 + 2 * 4 * PSH * 2;   // 152704 B
    hipFuncSetAttribute((const void*)cayley_kernel,
                        hipFuncAttributeMaxDynamicSharedMemorySize, (int)smem);
    hipLaunchKernelGGL(cayley_kernel, dim3(CLS), dim3(1024), smem, stream, x, W, out);
}

// Round 11
// 30.766 us; speedup vs baseline: 1.8156x; 1.8156x over previous
//
#include <hip/hip_runtime.h>

#define DIM   256
#define CLS   512
#define NGF   32640          // packed strict-upper-triangle floats per class
#define NQ    8160           // NGF/4 float4 quads
#define NITER 5
#define PSH   72             // y part stride in h16 (144 B -> part p banks {4p..4p+3})

typedef _Float16 h16;
typedef __attribute__((ext_vector_type(2))) _Float16 h16x2;

__device__ __forceinline__ float dot2f(unsigned a, unsigned b, float c) {
    return __builtin_amdgcn_fdot2(__builtin_bit_cast(h16x2, a),
                                  __builtin_bit_cast(h16x2, b), c, false);
}

__device__ __forceinline__ unsigned pkrtz(float lo, float hi) {
    return __builtin_bit_cast(unsigned, __builtin_amdgcn_cvt_pkrtz(lo, hi));
}

// barrier draining LDS only
__device__ __forceinline__ void bar_lds() {
    asm volatile("s_waitcnt lgkmcnt(0)\n\ts_barrier" ::: "memory");
}

__device__ __forceinline__ int cidx(int m) { return (m >> 6) * PSH + (m & 63); }

__global__ void __launch_bounds__(1024)
cayley_kernel(const float* __restrict__ x, const float* __restrict__ W,
              float* __restrict__ out) {
    extern __shared__ char smem[];
    unsigned short* U = (unsigned short*)smem;        // 65536 B: f16(0.5*W) packed triu
    h16* sy0 = (h16*)(smem + 65536);                  // 576 B
    h16* sy1 = sy0 + 4 * PSH;                         // 576 B

    const int tid  = threadIdx.x;
    const int r    = tid >> 2;       // row 0..255
    const int p    = tid & 3;        // part 0..3 (cols 64p..64p+63)
    const int c    = blockIdx.x;
    const int offr = (r * (511 - r)) / 2 - r - 1;     // off(r) - r - 1

    // ===== stage packed W -> LDS as f16 (0.5*w), coalesced =====
    {
        const float4* Wc4 = (const float4*)(W + (size_t)c * NGF);
        uint2* U2 = (uint2*)U;
        #pragma unroll
        for (int k = 0; k < 8; ++k) {
            int q = tid + 1024 * k;
            float4 v = Wc4[q < NQ ? q : 0];
            uint2 d;
            d.x = pkrtz(0.5f * v.x, 0.5f * v.y);
            d.y = pkrtz(0.5f * v.z, 0.5f * v.w);
            U2[q] = d;                                // 8 B/lane contiguous (q<8192 in-bounds)
        }
    }
    const float xr = x[(size_t)r * CLS + c];
    if (p == 0) sy0[cidx(r)] = (h16)xr;
    __syncthreads();                                  // U + y0 visible

    // ===== gather S[r][64p..64p+63] from packed f16 U into sreg (f16x2) =====
    // upper (g>r): +U[offr+g] (contiguous); lower (g<r): -U[off(g)+r-g-1] (recurrence)
    unsigned sreg[32];
    {
        const int g0 = p << 6;
        int au = offr + g0;
        int al = ((g0 * (511 - g0)) >> 1) + r - g0 - 1;
        int st = 254 - g0;                            // al step for j=0
        #pragma unroll
        for (int j = 0; j < 64; ++j) {
            int g = g0 + j;
            int idx = (g < r) ? al : au;
            idx = idx < 0 ? 0 : idx;
            unsigned h = U[idx];                      // zext u16 read
            h = (g < r) ? (h ^ 0x8000u) : h;          // lower = negated
            h = (g == r) ? 0u : h;                    // diagonal = 0
            if (j & 1) sreg[j >> 1] |= h << 16;
            else       sreg[j >> 1]  = h;
            ++au;
            al += st - j;                             // al(j+1) = al(j) + 254 - g
        }
    }

    // ===== fixed-point iteration y <- x - S y ; out = x - 2 S y =====
    {
        h16* ycur = sy0;
        h16* ynxt = sy1;
        for (int it = 0; it < NITER; ++it) {
            const uint4* yp = (const uint4*)(ycur + p * PSH);
            float a0 = 0.f, a1 = 0.f, a2 = 0.f, a3 = 0.f;
            #pragma unroll
            for (int k = 0; k < 8; ++k) {
                uint4 yv = yp[k];
                a0 = dot2f(sreg[4 * k + 0], yv.x, a0);
                a1 = dot2f(sreg[4 * k + 1], yv.y, a1);
                a2 = dot2f(sreg[4 * k + 2], yv.z, a2);
                a3 = dot2f(sreg[4 * k + 3], yv.w, a3);
            }
            float v = (a0 + a1) + (a2 + a3);          // partial (S y)_r
            v += __shfl_xor(v, 1);
            v += __shfl_xor(v, 2);                    // full (S y)_r on 4 lanes
            if (it < NITER - 1) {
                if (p == 0) ynxt[cidx(r)] = (h16)(xr - v);
                h16* t = ycur; ycur = ynxt; ynxt = t;
                bar_lds();
            } else {
                if (p == 0) out[(size_t)r * CLS + c] = xr - 2.f * v;
            }
        }
    }
}

extern "C" void kernel_launch(void* const* d_in, const int* in_sizes, int n_in,
                              void* d_out, int out_size, void* d_ws, size_t ws_size,
                              hipStream_t stream) {
    const float* x = (const float*)d_in[0];
    const float* W = (const float*)d_in[1];
    float* out = (float*)d_out;

    const size_t smem = 65536 + 2 * 4 * PSH * 2;      // 66688 B -> 2 blocks/CU
    hipFuncSetAttribute((const void*)cayley_kernel,
                        hipFuncAttributeMaxDynamicSharedMemorySize, (int)smem);
    hipLaunchKernelGGL(cayley_kernel, dim3(CLS), dim3(1024), smem, stream, x, W, out);
}

// Round 12
// 30.645 us; speedup vs baseline: 1.8228x; 1.0040x over previous
//
#include <hip/hip_runtime.h>

#define DIM   256
#define CLS   512
#define NGF   32640          // packed strict-upper-triangle floats per class
#define NQ    8160           // NGF/4 float4 quads
#define NITER 5
#define PSH   72             // y part-slice stride in h16 (144 B -> slice p at dw 36p mod 32 = 4p)

typedef _Float16 h16;
typedef __attribute__((ext_vector_type(2))) _Float16 h16x2;

__device__ __forceinline__ float dot2f(unsigned a, unsigned b, float c) {
    return __builtin_amdgcn_fdot2(__builtin_bit_cast(h16x2, a),
                                  __builtin_bit_cast(h16x2, b), c, false);
}

__device__ __forceinline__ unsigned pkrtz(float lo, float hi) {
    return __builtin_bit_cast(unsigned, __builtin_amdgcn_cvt_pkrtz(lo, hi));
}

// barrier draining LDS only
__device__ __forceinline__ void bar_lds() {
    asm volatile("s_waitcnt lgkmcnt(0)\n\ts_barrier" ::: "memory");
}

// y[g] lives at part(g)*PSH + slot(g): part = (g>>4)&3, slot = ((g>>6)<<4) | (g&15)
__device__ __forceinline__ int yaddr(int g) {
    return ((g >> 4) & 3) * PSH + (((g >> 6) << 4) | (g & 15));
}

__global__ void __launch_bounds__(1024, 8)   // 8 waves/EU = 2 blocks/CU; VGPR cap 64
cayley_kernel(const float* __restrict__ x, const float* __restrict__ W,
              float* __restrict__ out) {
    extern __shared__ char smem[];
    unsigned short* U = (unsigned short*)smem;        // 65536 B: f16(0.5*W) packed triu
    h16* sy0 = (h16*)(smem + 65536);                  // 576 B
    h16* sy1 = sy0 + 4 * PSH;                         // 576 B

    const int tid  = threadIdx.x;
    const int r    = tid >> 2;       // row 0..255
    const int p    = tid & 3;        // part 0..3: owns columns {64a + 16p + t}
    const int c    = blockIdx.x;
    const int offr = (r * (511 - r)) / 2 - r - 1;     // off(r) - r - 1

    // ===== stage packed W -> LDS as f16 (0.5*w), coalesced =====
    {
        const float4* Wc4 = (const float4*)(W + (size_t)c * NGF);
        uint2* U2 = (uint2*)U;
        #pragma unroll
        for (int k = 0; k < 8; ++k) {
            int q = tid + 1024 * k;
            float4 v = Wc4[q < NQ ? q : 0];
            uint2 d;
            d.x = pkrtz(0.5f * v.x, 0.5f * v.y);
            d.y = pkrtz(0.5f * v.z, 0.5f * v.w);
            U2[q] = d;                                // 8 B/lane contiguous
        }
    }
    const float xr = x[(size_t)r * CLS + c];
    if (p == 0) sy0[yaddr(r)] = (h16)xr;
    __syncthreads();                                  // U + y0 visible

    // ===== gather S[r][g] for owned columns into sreg (f16x2), static slots =====
    // upper (g>r): +U[offr+g]; lower (g<r): -U[off(g)+r-g-1]; diag: 0
    unsigned sreg[32];
    {
        #pragma unroll
        for (int a = 0; a < 4; ++a) {
            int g  = 64 * a + 16 * p;
            int au = offr + g;
            int al = ((g * (511 - g)) >> 1) + r - g - 1;
            unsigned wacc = 0;
            #pragma unroll
            for (int t = 0; t < 16; ++t) {
                int idx = (g < r) ? al : au;
                idx = idx < 0 ? 0 : idx;              // only r==g==0 hits -1
                unsigned h = U[idx];                  // zext u16 read
                h = (g < r) ? (h ^ 0x8000u) : h;      // lower = negated
                h = (g == r) ? 0u : h;                // diagonal = 0
                if (t & 1) { wacc |= h << 16; sreg[(16 * a + t) >> 1] = wacc; }
                else       { wacc  = h; }
                ++au;
                al += 254 - g;                        // off(g+1)-off(g)-1 = 254-g
                ++g;
            }
        }
    }

    // ===== fixed-point iteration y <- x - S y ; out = x - 2 S y =====
    {
        h16* ycur = sy0;
        h16* ynxt = sy1;
        const int wr = yaddr(r);                      // this row's y slot
        for (int it = 0; it < NITER; ++it) {
            const uint4* yp = (const uint4*)(ycur + p * PSH);
            float a0 = 0.f, a1 = 0.f, a2 = 0.f, a3 = 0.f;
            #pragma unroll
            for (int k = 0; k < 8; ++k) {
                uint4 yv = yp[k];
                a0 = dot2f(sreg[4 * k + 0], yv.x, a0);
                a1 = dot2f(sreg[4 * k + 1], yv.y, a1);
                a2 = dot2f(sreg[4 * k + 2], yv.z, a2);
                a3 = dot2f(sreg[4 * k + 3], yv.w, a3);
            }
            float v = (a0 + a1) + (a2 + a3);          // partial (S y)_r
            v += __shfl_xor(v, 1);
            v += __shfl_xor(v, 2);                    // full (S y)_r on 4 lanes
            if (it < NITER - 1) {
                if (p == 0) ynxt[wr] = (h16)(xr - v);
                h16* t = ycur; ycur = ynxt; ynxt = t;
                bar_lds();
            } else {
                if (p == 0) out[(size_t)r * CLS + c] = xr - 2.f * v;
            }
        }
    }
}

extern "C" void kernel_launch(void* const* d_in, const int* in_sizes, int n_in,
                              void* d_out, int out_size, void* d_ws, size_t ws_size,
                              hipStream_t stream) {
    const float* x = (const float*)d_in[0];
    const float* W = (const float*)d_in[1];
    float* out = (float*)d_out;

    const size_t smem = 65536 + 2 * 4 * PSH * 2;      // 66688 B -> 2 blocks/CU
    hipFuncSetAttribute((const void*)cayley_kernel,
                        hipFuncAttributeMaxDynamicSharedMemorySize, (int)smem);
    hipLaunchKernelGGL(cayley_kernel, dim3(CLS), dim3(1024), smem, stream, x, W, out);
}